// Round 3
// baseline (1150.464 us; speedup 1.0000x reference)
//
#include <hip/hip_runtime.h>
#include <math.h>

#define IN 8000
#define OC 10
#define DD 16
#define SVOL (64 * OC * DD)   // 10240 floats: one per-chunk partial [b][o][d]

// Kernel A: grid (nchunk, 8). blockIdx.y = bg (8 batches), blockIdx.x = chunk.
// nchunk is a multiple of 8 so all 8 bg-copies of a chunk land on one XCD
// (linear blockIdx round-robin) -> W's L2 amplification stays intra-XCD.
// Block = 256 thr = 4 independent waves (no in-loop barriers); wave w takes
// i = i0 + w + 4*j. Lane = (bl:3 | oh:1 | t4:2): thread owns batch b=bg*8+bl,
// o in [5*oh, 5*oh+5), d in [4*t4, 4*t4+4). W and x read straight from global
// (coalesced 32-B segments, L1/L2 serve the 8/16-lane broadcast); no LDS in
// the hot loop. Softmax: t4-reduce via shfl_xor(1,2), o-half swap via
// shfl_xor(4). End: 4-wave LDS tree reduce, one partial per (chunk,bg).
template<int UNIFORM>
__global__ __launch_bounds__(256, 4) void caps_pass(
    const float* __restrict__ W, const float* __restrict__ x,
    const float* __restrict__ Vacc, float* __restrict__ part, int ci)
{
    const int t    = threadIdx.x;
    const int w    = t >> 6;
    const int lane = t & 63;
    const int bl   = lane >> 3;
    const int oh   = (lane >> 2) & 1;
    const int t4   = lane & 3;
    const int bg   = blockIdx.y;
    const int b    = bg * 8 + bl;
    const int i0   = blockIdx.x * ci;
    int iend = i0 + ci;
    if (iend > IN) iend = IN;

    float vac[5][4];
    if (!UNIFORM) {
        const float* vp = Vacc + b * (OC * DD) + (oh * 5) * DD + t4 * 4;
#pragma unroll
        for (int j = 0; j < 5; ++j) {
            float4 v4 = *(const float4*)(vp + j * DD);
            vac[j][0] = v4.x; vac[j][1] = v4.y; vac[j][2] = v4.z; vac[j][3] = v4.w;
        }
    }

    float acc[5][4];
#pragma unroll
    for (int j = 0; j < 5; ++j)
#pragma unroll
        for (int k = 0; k < 4; ++k) acc[j][k] = 0.f;

    // per-thread invariant bases
    const float* bW = W + (size_t)(oh * 5) * (IN * 128) + t4 * 32;
    const float* bx = x + (size_t)b * (IN * 8);

    for (int i = i0 + w; i < iend; i += 4) {
        const float* wi = bW + (size_t)i * 128;
        const float* xp = bx + (size_t)i * 8;
        float4 xa = *(const float4*)(xp);
        float4 xb = *(const float4*)(xp + 4);

        float uh[5][4];
        float lg[5];
#pragma unroll
        for (int j = 0; j < 5; ++j) {
            const float* wj = wi + (size_t)j * (IN * 128);
            float lgj = 0.f;
#pragma unroll
            for (int k = 0; k < 4; ++k) {
                float4 wa = *(const float4*)(wj + k * 8);
                float4 wb = *(const float4*)(wj + k * 8 + 4);
                float u = wa.x * xa.x + wa.y * xa.y + wa.z * xa.z + wa.w * xa.w
                        + wb.x * xb.x + wb.y * xb.y + wb.z * xb.z + wb.w * xb.w;
                if (UNIFORM) {
                    acc[j][k] += 0.1f * u;
                } else {
                    uh[j][k] = u;
                    lgj += u * vac[j][k];
                }
            }
            lg[j] = lgj;
        }

        if (!UNIFORM) {
            // reduce logits over d (t4 lanes: xor 1, 2 stay in-quad -> DPP)
#pragma unroll
            for (int j = 0; j < 5; ++j) {
                lg[j] += __shfl_xor(lg[j], 1);
                lg[j] += __shfl_xor(lg[j], 2);
            }
            // swap o-halves (xor 4)
            float lo[5];
#pragma unroll
            for (int j = 0; j < 5; ++j) lo[j] = __shfl_xor(lg[j], 4);
            float mx = lg[0];
#pragma unroll
            for (int j = 1; j < 5; ++j) mx = fmaxf(mx, lg[j]);
#pragma unroll
            for (int j = 0; j < 5; ++j) mx = fmaxf(mx, lo[j]);
            float c[5];
            float se = 0.f;
#pragma unroll
            for (int j = 0; j < 5; ++j) { c[j] = __expf(lg[j] - mx); se += c[j]; }
#pragma unroll
            for (int j = 0; j < 5; ++j) se += __expf(lo[j] - mx);
            float rs = 1.f / se;
#pragma unroll
            for (int j = 0; j < 5; ++j) {
                float cj = c[j] * rs;
#pragma unroll
                for (int k = 0; k < 4; ++k) acc[j][k] += cj * uh[j][k];
            }
        }
    }

    // cross-wave reduce (only barriers in the kernel)
    __shared__ float red[8 * OC * DD];   // 5 KB
    const int r = bl * (OC * DD) + (oh * 5) * DD + t4 * 4;
    __syncthreads();
    if (w == 0) {
#pragma unroll
        for (int j = 0; j < 5; ++j)
#pragma unroll
            for (int k = 0; k < 4; ++k) red[r + j * DD + k] = acc[j][k];
    }
    __syncthreads();
    if (w == 1) {
#pragma unroll
        for (int j = 0; j < 5; ++j)
#pragma unroll
            for (int k = 0; k < 4; ++k) red[r + j * DD + k] += acc[j][k];
    }
    __syncthreads();
    if (w == 2) {
#pragma unroll
        for (int j = 0; j < 5; ++j)
#pragma unroll
            for (int k = 0; k < 4; ++k) red[r + j * DD + k] += acc[j][k];
    }
    __syncthreads();
    if (w == 3) {
#pragma unroll
        for (int j = 0; j < 5; ++j)
#pragma unroll
            for (int k = 0; k < 4; ++k) red[r + j * DD + k] += acc[j][k];
    }
    __syncthreads();
    if (w == 0) {
        float4* dst = (float4*)(part + (size_t)blockIdx.x * SVOL + bg * (8 * OC * DD));
        const float4* src = (const float4*)red;
        for (int q = lane; q < (8 * OC * DD) / 4; q += 64) dst[q] = src[q];
    }
}

// Kernel B: one block per (b,o). Reduce partials over chunks, squash,
// write Vacc (mode 0 = overwrite, 1 = accumulate) or final out (mode 2).
__global__ __launch_bounds__(256) void caps_reduce(
    const float* __restrict__ part, float* __restrict__ Vacc,
    float* __restrict__ out, int nchunk, int mode)
{
    const int bo = blockIdx.x;      // b*10+o, [0,640)
    const int t  = threadIdx.x;
    const int d  = t & 15;
    const int s  = t >> 4;          // 16 slices over chunks
    const int b  = bo / 10;
    const int o  = bo - b * 10;

    const float* base = part + b * (OC * DD) + o * DD + d;
    float acc = 0.f;
    for (int c = s; c < nchunk; c += 16)
        acc += base[(size_t)c * SVOL];

    __shared__ float red[16][17];
    red[s][d] = acc;
    __syncthreads();
    if (t < 16) {
        float sv = 0.f;
#pragma unroll
        for (int s2 = 0; s2 < 16; ++s2) sv += red[s2][t];
        float n2 = sv * sv;
#pragma unroll
        for (int m = 1; m < 16; m <<= 1) n2 += __shfl_xor(n2, m);
        float norm  = sqrtf(n2);
        float scale = n2 / (1.f + n2) / (norm + 1e-8f);
        float v = scale * sv;
        if (mode == 2)      out[bo * DD + t] = v;
        else if (mode == 0) Vacc[bo * DD + t] = v;
        else                Vacc[bo * DD + t] += v;
    }
}

extern "C" void kernel_launch(void* const* d_in, const int* in_sizes, int n_in,
                              void* d_out, int out_size, void* d_ws, size_t ws_size,
                              hipStream_t stream) {
    const float* x = (const float*)d_in[0];   // (64, 8000, 8)
    const float* W = (const float*)d_in[1];   // (10, 8000, 16, 8)
    float* out = (float*)d_out;               // (64, 10, 16)

    char* ws = (char*)d_ws;
    float* Vacc = (float*)ws;                             // 40 KB
    float* part = (float*)(ws + SVOL * sizeof(float));    // nchunk * 40 KB

    size_t avail = (ws_size > SVOL * sizeof(float)) ? ws_size - SVOL * sizeof(float) : 0;
    int nchunk = (int)(avail / (SVOL * sizeof(float)));
    if (nchunk > 200) nchunk = 200;
    nchunk &= ~7;                 // multiple of 8 for the XCD swizzle
    if (nchunk < 1) nchunk = 1;
    int ci = (IN + nchunk - 1) / nchunk;

    dim3 grid(nchunk, 8);   // chunk fastest: bg-copies of a chunk share an XCD

    // iter 0: uniform c = 0.1 (b-logits all zero)
    caps_pass<1><<<grid, 256, 0, stream>>>(W, x, Vacc, part, ci);
    caps_reduce<<<640, 256, 0, stream>>>(part, Vacc, out, nchunk, 0);
    // iter 1
    caps_pass<0><<<grid, 256, 0, stream>>>(W, x, Vacc, part, ci);
    caps_reduce<<<640, 256, 0, stream>>>(part, Vacc, out, nchunk, 1);
    // iter 2 (final): write v to out
    caps_pass<0><<<grid, 256, 0, stream>>>(W, x, Vacc, part, ci);
    caps_reduce<<<640, 256, 0, stream>>>(part, Vacc, out, nchunk, 2);
}

// Round 4
// 217.574 us; speedup vs baseline: 5.2877x; 5.2877x over previous
//
#include <hip/hip_runtime.h>
#include <hip/hip_fp16.h>
#include <math.h>

#define IN 8000
#define OC 10
#define SVOL (64 * OC * 16)   // 10240 floats per partial [b][o][d]

typedef __fp16 h2 __attribute__((ext_vector_type(2)));

__device__ __forceinline__ h2 asb(unsigned int v) { return __builtin_bit_cast(h2, v); }

__device__ __forceinline__ float dot2(h2 a, h2 b, float c) {
#if __has_builtin(__builtin_amdgcn_fdot2)
    return __builtin_amdgcn_fdot2(a, b, c, false);
#else
    return fmaf((float)a[0], (float)b[0], fmaf((float)a[1], (float)b[1], c));
#endif
}

__device__ __forceinline__ unsigned int pk_rn(float a, float b) {
    return __builtin_bit_cast(unsigned int, __float22half2_rn(make_float2(a, b)));
}

// Kernel A: grid = nchunk blocks x 1024 thr (16 waves = 4 bh x 4 ih).
// Lane = (bl:3 | oh:1 | t4:2). Thread owns b in {bh*16+bl, bh*16+bl+8},
// o in [5*oh, 5*oh+5), d in [4*t4, 4*t4+4). W and x staged per 16-i tile
// into LDS as f16 (RNE); hot loop: 20 W-b128 + 2 x-b128 per lane-i feeding
// 640 MACs via v_dot2_f32_f16 (fp32 accum). Softmax fully in-wave:
// d-reduce shfl_xor(1,2), o-half swap shfl_xor(4). 4-round LDS block
// reduce at the end (red aliases W tile), one fp32 partial per chunk.
template<int UNIFORM>
__global__ __launch_bounds__(1024) void caps_pass(
    const float* __restrict__ W, const float* __restrict__ x,
    const float* __restrict__ Vacc, float* __restrict__ part, int ci)
{
    __shared__ __align__(16) unsigned short Wl[16 * OC * 136];  // 43520 B (>= 40960 for red alias)
    __shared__ __align__(16) unsigned short xl[16 * 520];       // 16640 B

    const int t    = threadIdx.x;
    const int w    = t >> 6;
    const int bh   = w >> 2;
    const int ih   = w & 3;
    const int lane = t & 63;
    const int bl   = lane >> 3;
    const int oh   = (lane >> 2) & 1;
    const int t4   = lane & 3;
    const int b0   = bh * 16 + bl;     // second batch: b0 + 8
    const int i0   = blockIdx.x * ci;
    const int iend = min(i0 + ci, IN);

    h2 vac[2][5][2];
    if (!UNIFORM) {
#pragma unroll
        for (int j = 0; j < 2; ++j) {
            const float* vp = Vacc + (size_t)(b0 + j * 8) * (OC * 16) + (oh * 5) * 16 + t4 * 4;
#pragma unroll
            for (int jo = 0; jo < 5; ++jo) {
                float4 v4 = *(const float4*)(vp + jo * 16);
                vac[j][jo][0] = asb(pk_rn(v4.x, v4.y));
                vac[j][jo][1] = asb(pk_rn(v4.z, v4.w));
            }
        }
    }

    float acc[2][5][4];
#pragma unroll
    for (int j = 0; j < 2; ++j)
#pragma unroll
        for (int jo = 0; jo < 5; ++jo)
#pragma unroll
            for (int k = 0; k < 4; ++k) acc[j][jo][k] = 0.f;

    for (int is = i0; is < iend; is += 16) {
        const int nst = min(16, iend - is);
        __syncthreads();
        // stage W: nst*320 float4 -> f16
        for (int j = t; j < nst * 320; j += 1024) {
            int iw = j / 320;
            int r  = j - iw * 320;
            int o  = r >> 5;
            int f  = r & 31;
            float4 w4 = *(const float4*)(W + (size_t)o * (IN * 128) +
                                         (size_t)(is + iw) * 128 + f * 4);
            *(uint2*)&Wl[iw * 1360 + o * 136 + f * 4] =
                make_uint2(pk_rn(w4.x, w4.y), pk_rn(w4.z, w4.w));
        }
        // stage x: nst*128 float4 -> f16
        if (nst == 16) {
            for (int j = t; j < 16 * 128; j += 1024) {
                int bb = j >> 5;
                int r  = j & 31;
                int iw = r >> 1;
                int hh = r & 1;
                float4 x4 = *(const float4*)(x + (size_t)bb * (IN * 8) +
                                             (size_t)(is + iw) * 8 + hh * 4);
                *(uint2*)&xl[iw * 520 + bb * 8 + hh * 4] =
                    make_uint2(pk_rn(x4.x, x4.y), pk_rn(x4.z, x4.w));
            }
        } else {
            for (int j = t; j < nst * 128; j += 1024) {
                int bb = j / (nst * 2);
                int r  = j - bb * (nst * 2);
                int iw = r >> 1;
                int hh = r & 1;
                float4 x4 = *(const float4*)(x + (size_t)bb * (IN * 8) +
                                             (size_t)(is + iw) * 8 + hh * 4);
                *(uint2*)&xl[iw * 520 + bb * 8 + hh * 4] =
                    make_uint2(pk_rn(x4.x, x4.y), pk_rn(x4.z, x4.w));
            }
        }
        __syncthreads();

#pragma unroll 1
        for (int u = 0; u < 4; ++u) {
            const int i = is + ih * 4 + u;
            if (i >= iend) break;
            const unsigned short* wp = &Wl[(i - is) * 1360 + (oh * 5) * 136 + t4 * 32];
            const unsigned short* xp = &xl[(i - is) * 520];

            uint4 xq0 = *(const uint4*)(xp + b0 * 8);
            uint4 xq1 = *(const uint4*)(xp + (b0 + 8) * 8);
            h2 xv[2][4];
            xv[0][0] = asb(xq0.x); xv[0][1] = asb(xq0.y); xv[0][2] = asb(xq0.z); xv[0][3] = asb(xq0.w);
            xv[1][0] = asb(xq1.x); xv[1][1] = asb(xq1.y); xv[1][2] = asb(xq1.z); xv[1][3] = asb(xq1.w);

            float lg[2][5];
            h2 uh[2][5][2];
#pragma unroll
            for (int jo = 0; jo < 5; ++jo) {
                const unsigned short* wo = wp + jo * 136;
                uint4 q0 = *(const uint4*)(wo);        // d = 4*t4+0, e0..7
                uint4 q1 = *(const uint4*)(wo + 8);    // d = 4*t4+1
                uint4 q2 = *(const uint4*)(wo + 16);   // d = 4*t4+2
                uint4 q3 = *(const uint4*)(wo + 24);   // d = 4*t4+3
#pragma unroll
                for (int j = 0; j < 2; ++j) {
                    float u0 = dot2(asb(q0.x), xv[j][0], 0.f);
                    u0 = dot2(asb(q0.y), xv[j][1], u0);
                    u0 = dot2(asb(q0.z), xv[j][2], u0);
                    u0 = dot2(asb(q0.w), xv[j][3], u0);
                    float u1 = dot2(asb(q1.x), xv[j][0], 0.f);
                    u1 = dot2(asb(q1.y), xv[j][1], u1);
                    u1 = dot2(asb(q1.z), xv[j][2], u1);
                    u1 = dot2(asb(q1.w), xv[j][3], u1);
                    float u2 = dot2(asb(q2.x), xv[j][0], 0.f);
                    u2 = dot2(asb(q2.y), xv[j][1], u2);
                    u2 = dot2(asb(q2.z), xv[j][2], u2);
                    u2 = dot2(asb(q2.w), xv[j][3], u2);
                    float u3 = dot2(asb(q3.x), xv[j][0], 0.f);
                    u3 = dot2(asb(q3.y), xv[j][1], u3);
                    u3 = dot2(asb(q3.z), xv[j][2], u3);
                    u3 = dot2(asb(q3.w), xv[j][3], u3);
                    if (UNIFORM) {
                        acc[j][jo][0] += u0;  // c=0.1 folded into reduce scale
                        acc[j][jo][1] += u1;
                        acc[j][jo][2] += u2;
                        acc[j][jo][3] += u3;
                    } else {
                        h2 p0 = __builtin_amdgcn_cvt_pkrtz(u0, u1);
                        h2 p1 = __builtin_amdgcn_cvt_pkrtz(u2, u3);
                        uh[j][jo][0] = p0;
                        uh[j][jo][1] = p1;
                        lg[j][jo] = dot2(p0, vac[j][jo][0], dot2(p1, vac[j][jo][1], 0.f));
                    }
                }
            }

            if (!UNIFORM) {
#pragma unroll
                for (int j = 0; j < 2; ++j) {
#pragma unroll
                    for (int jo = 0; jo < 5; ++jo) {
                        lg[j][jo] += __shfl_xor(lg[j][jo], 1);
                        lg[j][jo] += __shfl_xor(lg[j][jo], 2);
                    }
                    float lo[5];
#pragma unroll
                    for (int jo = 0; jo < 5; ++jo) lo[jo] = __shfl_xor(lg[j][jo], 4);
                    float mx = lg[j][0];
#pragma unroll
                    for (int jo = 1; jo < 5; ++jo) mx = fmaxf(mx, lg[j][jo]);
#pragma unroll
                    for (int jo = 0; jo < 5; ++jo) mx = fmaxf(mx, lo[jo]);
                    float c[5];
                    float se = 0.f;
#pragma unroll
                    for (int jo = 0; jo < 5; ++jo) { c[jo] = __expf(lg[j][jo] - mx); se += c[jo]; }
#pragma unroll
                    for (int jo = 0; jo < 5; ++jo) se += __expf(lo[jo] - mx);
                    float rs = 1.f / se;
#pragma unroll
                    for (int jo = 0; jo < 5; ++jo) {
                        float cj = c[jo] * rs;
                        acc[j][jo][0] += cj * (float)uh[j][jo][0][0];
                        acc[j][jo][1] += cj * (float)uh[j][jo][0][1];
                        acc[j][jo][2] += cj * (float)uh[j][jo][1][0];
                        acc[j][jo][3] += cj * (float)uh[j][jo][1][1];
                    }
                }
            }
        }
    }

    // block reduce over the 4 ih-waves (red aliases Wl), then store partial
    float* red = (float*)Wl;
#pragma unroll 1
    for (int r = 0; r < 4; ++r) {
        __syncthreads();
        if (ih == r) {
#pragma unroll
            for (int j = 0; j < 2; ++j) {
#pragma unroll
                for (int jo = 0; jo < 5; ++jo) {
                    float* p = &red[(size_t)(b0 + j * 8) * 160 + (oh * 5 + jo) * 16 + t4 * 4];
                    if (r == 0) {
                        *(float4*)p = make_float4(acc[j][jo][0], acc[j][jo][1],
                                                  acc[j][jo][2], acc[j][jo][3]);
                    } else {
                        float4 v = *(const float4*)p;
                        v.x += acc[j][jo][0]; v.y += acc[j][jo][1];
                        v.z += acc[j][jo][2]; v.w += acc[j][jo][3];
                        *(float4*)p = v;
                    }
                }
            }
        }
    }
    __syncthreads();
    float4* dst = (float4*)(part + (size_t)blockIdx.x * SVOL);
    const float4* src = (const float4*)red;
    for (int q = t; q < SVOL / 4; q += 1024) dst[q] = src[q];
}

// Kernel B: one block per (b,o). Reduce partials over chunks, scale, squash,
// write Vacc (mode 0 = overwrite, 1 = accumulate) or final out (mode 2).
__global__ __launch_bounds__(256) void caps_reduce(
    const float* __restrict__ part, float* __restrict__ Vacc,
    float* __restrict__ out, int nchunk, int mode, float scale)
{
    const int bo = blockIdx.x;      // b*10+o, [0,640)
    const int t  = threadIdx.x;
    const int d  = t & 15;
    const int s  = t >> 4;          // 16 slices over chunks

    const float* base = part + (size_t)bo * 16 + d;
    float acc = 0.f;
    for (int c = s; c < nchunk; c += 16)
        acc += base[(size_t)c * SVOL];

    __shared__ float red[16][17];
    red[s][d] = acc;
    __syncthreads();
    if (t < 16) {
        float sv = 0.f;
#pragma unroll
        for (int s2 = 0; s2 < 16; ++s2) sv += red[s2][t];
        sv *= scale;
        float n2 = sv * sv;
#pragma unroll
        for (int m = 1; m < 16; m <<= 1) n2 += __shfl_xor(n2, m);
        float norm  = sqrtf(n2);
        float scl = n2 / (1.f + n2) / (norm + 1e-8f);
        float v = scl * sv;
        if (mode == 2)      out[bo * 16 + t] = v;
        else if (mode == 0) Vacc[bo * 16 + t] = v;
        else                Vacc[bo * 16 + t] += v;
    }
}

extern "C" void kernel_launch(void* const* d_in, const int* in_sizes, int n_in,
                              void* d_out, int out_size, void* d_ws, size_t ws_size,
                              hipStream_t stream) {
    const float* x = (const float*)d_in[0];   // (64, 8000, 8)
    const float* W = (const float*)d_in[1];   // (10, 8000, 16, 8)
    float* out = (float*)d_out;               // (64, 10, 16)

    char* ws = (char*)d_ws;
    float* Vacc = (float*)ws;                             // 40 KB
    float* part = (float*)(ws + SVOL * sizeof(float));    // nchunk * 40 KB

    size_t avail = (ws_size > SVOL * sizeof(float)) ? ws_size - SVOL * sizeof(float) : 0;
    int nchunk = (int)(avail / (SVOL * sizeof(float)));
    if (nchunk > 250) nchunk = 250;
    if (nchunk < 1)   nchunk = 1;
    int ci = (IN + nchunk - 1) / nchunk;
    nchunk = (IN + ci - 1) / ci;

    // iter 0: uniform c (0.1 folded into reduce scale)
    caps_pass<1><<<nchunk, 1024, 0, stream>>>(W, x, Vacc, part, ci);
    caps_reduce<<<640, 256, 0, stream>>>(part, Vacc, out, nchunk, 0, 0.1f);
    // iter 1
    caps_pass<0><<<nchunk, 1024, 0, stream>>>(W, x, Vacc, part, ci);
    caps_reduce<<<640, 256, 0, stream>>>(part, Vacc, out, nchunk, 1, 1.0f);
    // iter 2 (final): write v to out
    caps_pass<0><<<nchunk, 1024, 0, stream>>>(W, x, Vacc, part, ci);
    caps_reduce<<<640, 256, 0, stream>>>(part, Vacc, out, nchunk, 2, 1.0f);
}